// Round 6
// baseline (569.062 us; speedup 1.0000x reference)
//
#include <hip/hip_runtime.h>
#include <math.h>

#define NN 100000
#define DF 512
#define HID 16
#define NBUCK 392            // ceil(NN/256) buckets of 256 dst values
#define EPB 4096             // edges per block in bucketA (256 thr x 16)
#define BCAP 7800            // bucketB LDS staging capacity (62.4 KB)

#define GTN 256              // gemm: nodes per block (4 waves x 64)
#define GKC 32               // gemm: k-chunk (floats)
#define GNCH (DF / GKC)      // 16 chunks
#define GLROW 33             // wave-private LDS row stride: (l+kk)%32 -> 2-way = free
#define HISTB 128            // hist-role blocks fused into front_kernel

// Flag: 1 if edge_index is int64-laid-out, 0 if int32.
__device__ int g_idx64;

__global__ void detect_idx_kernel(const long long* __restrict__ idx,
                                  int* __restrict__ bcnt) {
    int lane = threadIdx.x;  // 64 threads
    int ok = 1;
    for (int i = lane; i < 128; i += 64) {
        long long v = idx[i];
        if (v < 0 || v >= NN) ok = 0;
    }
    unsigned long long m = __ballot(ok);
    if (lane == 0) g_idx64 = (m == ~0ULL);
    for (int i = lane; i < NBUCK; i += 64) bcnt[i] = 0;   // replaces memset
}

// ---------------- front: gemm1 (h1 = x @ W1) + bucket hist, fused ----------
// Gemm role: 4 waves/block, each wave owns a PRIVATE 64-node LDS slice ->
// ZERO __syncthreads. Rationale: barriers drain vmcnt AND lgkmcnt (SMEM!),
// killing the W1 s_load pipeline 8x/block (round-5 evidence: deeper x
// prefetch was null). Wave-private staging keeps same-wave DS ordering
// (program order) and never drains the scalar queue. W1 address has no
// threadIdx dependence -> provably uniform -> s_load path (round-4 lesson).
// 33.8 KB LDS -> 4 blocks/CU = 4 waves/SIMD (2x round-5 occupancy).
// Hist role: same launch, separate blocks; runs concurrently (free).
__global__ __launch_bounds__(256, 4) void front_kernel(
    const float* __restrict__ x, const float* __restrict__ W1,
    float* __restrict__ h1, const void* __restrict__ eidx,
    int* __restrict__ bcnt, int nN, int nE, int gemmBlocks)
{
    __shared__ float sx[4][64 * GLROW];  // 33.8 KB, wave-private slices
    __shared__ int hh[NBUCK];            // 1.6 KB (hist role only)
    const int b = blockIdx.x;
    const int t = threadIdx.x;

    if (b >= gemmBlocks) {
        // ---------------- hist role ----------------
        for (int i = t; i < NBUCK; i += 256) hh[i] = 0;
        __syncthreads();
        const int i64 = g_idx64;
        int stride = HISTB * 256;
        int tid = (b - gemmBlocks) * 256 + t;
        if ((nE & 1) == 0) {
            int nE2 = nE >> 1;
            if (i64) {
                const int4* dp = (const int4*)((const long long*)eidx + nE);
                for (int i = tid; i < nE2; i += stride) {
                    int4 d = dp[i];
                    if (d.y == 0 && (unsigned)d.x < (unsigned)NN) atomicAdd(&hh[d.x >> 8], 1);
                    if (d.w == 0 && (unsigned)d.z < (unsigned)NN) atomicAdd(&hh[d.z >> 8], 1);
                }
            } else {
                const int2* dp = (const int2*)((const int*)eidx + nE);
                for (int i = tid; i < nE2; i += stride) {
                    int2 d = dp[i];
                    if ((unsigned)d.x < (unsigned)NN) atomicAdd(&hh[d.x >> 8], 1);
                    if ((unsigned)d.y < (unsigned)NN) atomicAdd(&hh[d.y >> 8], 1);
                }
            }
        } else {
            for (int e = tid; e < nE; e += stride) {
                int d;
                if (i64) d = (int)((const long long*)eidx)[nE + e];
                else     d = ((const int*)eidx)[nE + e];
                if ((unsigned)d < (unsigned)NN) atomicAdd(&hh[d >> 8], 1);
            }
        }
        __syncthreads();
        for (int i = t; i < NBUCK; i += 256)
            if (hh[i]) atomicAdd(&bcnt[i], hh[i]);
        return;
    }

    // ---------------- gemm role ----------------
    const int w = t >> 6;                 // wave 0..3
    const int l = t & 63;
    float* sw = sx[w];
    const int wbase = b * GTN + w * 64;   // first node of this wave

    const float4* x4 = (const float4*)x;
    int rowg[8];
#pragma unroll
    for (int i = 0; i < 8; ++i) {
        int r = wbase + i * 8 + (l >> 3);
        rowg[i] = (r < nN) ? r : (nN - 1);    // clamp: dup loads, harmless
    }

    float acc[16];
#pragma unroll
    for (int c = 0; c < 16; ++c) acc[c] = 0.f;

    float4 pfA[8], pfB[8];

    auto issue = [&](float4* buf, int kc) {
        // 8 lanes read 128B-contiguous per row; 8 rows per instr
#pragma unroll
        for (int i = 0; i < 8; ++i)
            buf[i] = x4[(size_t)rowg[i] * (DF / 4) + kc * 8 + (l & 7)];
    };
    auto stage = [&](float4* buf) {
        // banks: (row + col) % 32 over 64 lanes -> exactly 2-way = free
#pragma unroll
        for (int i = 0; i < 8; ++i) {
            int a = (i * 8 + (l >> 3)) * GLROW + (l & 7) * 4;
            sw[a + 0] = buf[i].x; sw[a + 1] = buf[i].y;
            sw[a + 2] = buf[i].z; sw[a + 3] = buf[i].w;
        }
    };
    auto compute = [&](int kc) {
        const float* xr = sw + l * GLROW;
        const float* wb = W1 + kc * GKC * HID;   // no tid dep -> s_load
#pragma unroll
        for (int kk = 0; kk < GKC; ++kk) {
            float s = xr[kk];
            const float* wr = wb + kk * HID;
#pragma unroll
            for (int c = 0; c < 16; ++c)
                acc[c] = fmaf(s, wr[c], acc[c]);
        }
    };

    issue(pfA, 0);
    issue(pfB, 1);
    for (int kc = 0; kc < GNCH; kc += 2) {
        stage(pfA);
        if (kc + 2 < GNCH) issue(pfA, kc + 2);
        compute(kc);
        stage(pfB);
        if (kc + 3 < GNCH) issue(pfB, kc + 3);
        compute(kc + 1);
    }

    int gn = wbase + l;
    if (gn < nN) {
        float4* o = (float4*)(h1 + (size_t)gn * HID);
#pragma unroll
        for (int g = 0; g < 4; ++g)
            o[g] = make_float4(acc[g * 4 + 0], acc[g * 4 + 1],
                               acc[g * 4 + 2], acc[g * 4 + 3]);
    }
}

// ---------------- Scan of 392 bucket counts -> bbase / cursor --------------
__global__ __launch_bounds__(512) void bucket_scan_kernel(
    const int* __restrict__ bcnt, int* __restrict__ bbase,
    int* __restrict__ cursor, int* __restrict__ rowStart)
{
    __shared__ int s[512];
    int t = threadIdx.x;
    int v = (t < NBUCK) ? bcnt[t] : 0;
    s[t] = v;
    __syncthreads();
    for (int off = 1; off < 512; off <<= 1) {
        int u = (t >= off) ? s[t - off] : 0;
        __syncthreads();
        s[t] += u;
        __syncthreads();
    }
    int excl = s[t] - v;   // exclusive prefix
    if (t < NBUCK) { bbase[t] = excl; cursor[t] = excl; }
    if (t == NBUCK) bbase[t] = excl;          // == total
    if (t == NBUCK) rowStart[NN] = excl;
}

// ---------------- Pass A: coarse bucket sort -------------------------------
// Edge loads vectorized as pairs (int4/int2/float2) when E is even.
__global__ __launch_bounds__(256) void bucketA_kernel(
    const void* __restrict__ eidx, const float* __restrict__ ew,
    int* __restrict__ cursor, int2* __restrict__ packed, int nE)
{
    __shared__ int cnt[NBUCK];
    __shared__ int base[NBUCK];
    int t = threadIdx.x;
    for (int i = t; i < NBUCK; i += 256) cnt[i] = 0;
    __syncthreads();

    const int e0 = blockIdx.x * EPB;
    const int i64 = g_idx64;
    int lo[16]; float wv[16]; int bk[16];

    auto classify = [&](int slot, int s, int d, float w, bool valid) {
        bk[slot] = -1;
        if (valid && (unsigned)d < (unsigned)NN) {
            if ((unsigned)s >= (unsigned)NN) { s = 0; w = 0.f; }
            bk[slot] = d >> 8;
            lo[slot] = s | ((d & 255) << 20);
            wv[slot] = w;
            atomicAdd(&cnt[bk[slot]], 1);
        }
    };

    if ((nE & 1) == 0) {
        const int p0 = e0 >> 1;           // first pair of this block
        const int nP = nE >> 1;
        const float2* wp = (const float2*)ew;
#pragma unroll
        for (int i = 0; i < 8; ++i) {
            int p = p0 + t + i * 256;
            bool v = p < nP;
            int pc = v ? p : 0;
            int s0, s1, d0, d1;
            bool ok0 = v, ok1 = v;
            if (i64) {
                const int4* sp = (const int4*)eidx;
                const int4* dp = (const int4*)((const long long*)eidx + nE);
                int4 s4 = sp[pc]; int4 d4 = dp[pc];
                s0 = s4.x; s1 = s4.z; d0 = d4.x; d1 = d4.z;
                ok0 = ok0 && (d4.y == 0); ok1 = ok1 && (d4.w == 0);
                if (s4.y != 0) s0 = -1;
                if (s4.w != 0) s1 = -1;
            } else {
                const int2* sp = (const int2*)eidx;
                const int2* dp = (const int2*)((const int*)eidx + nE);
                int2 s2 = sp[pc]; int2 d2 = dp[pc];
                s0 = s2.x; s1 = s2.y; d0 = d2.x; d1 = d2.y;
            }
            float2 w2 = wp[pc];
            classify(2 * i + 0, s0, d0, w2.x, ok0);
            classify(2 * i + 1, s1, d1, w2.y, ok1);
        }
    } else {
#pragma unroll
        for (int i = 0; i < 16; ++i) {
            int e = e0 + t + i * 256;
            bk[i] = -1;
            if (e < nE) {
                int s, d;
                if (i64) {
                    const long long* p = (const long long*)eidx;
                    s = (int)p[e]; d = (int)p[nE + e];
                } else {
                    const int* p = (const int*)eidx;
                    s = p[e]; d = p[nE + e];
                }
                classify(i, s, d, ew[e], true);
            }
        }
    }
    __syncthreads();
    for (int i = t; i < NBUCK; i += 256)
        base[i] = (cnt[i] > 0) ? atomicAdd(&cursor[i], cnt[i]) : 0;
    __syncthreads();
    for (int i = t; i < NBUCK; i += 256) cnt[i] = 0;
    __syncthreads();
#pragma unroll
    for (int i = 0; i < 16; ++i) {
        if (bk[i] >= 0) {
            int r = atomicAdd(&cnt[bk[i]], 1);
            packed[base[bk[i]] + r] = make_int2(lo[i], __float_as_int(wv[i]));
        }
    }
}

// ---------------- Pass B: per-bucket fine CSR, single global read ----------
__global__ __launch_bounds__(256) void bucketB_kernel(
    const int2* __restrict__ packed, const int* __restrict__ bbase,
    int* __restrict__ rowStart, int2* __restrict__ se, int nN)
{
    __shared__ int hcnt[256];
    __shared__ int wtot[4];
    __shared__ int2 stage[BCAP];
    int b = blockIdx.x;
    int t = threadIdx.x;
    int beg = bbase[b], end = bbase[b + 1];
    int cnt = end - beg;

    hcnt[t] = 0;
    __syncthreads();
    for (int i = t; i < cnt; i += 256) {
        int2 e = packed[beg + i];
        if (i < BCAP) stage[i] = e;
        atomicAdd(&hcnt[(e.x >> 20) & 255], 1);
    }
    __syncthreads();

    // exclusive scan of hcnt[256]: shfl within waves + wave offsets
    int v = hcnt[t];
    int incl = v;
#pragma unroll
    for (int off = 1; off < 64; off <<= 1) {
        int u = __shfl_up(incl, off, 64);
        if ((t & 63) >= off) incl += u;
    }
    if ((t & 63) == 63) wtot[t >> 6] = incl;
    __syncthreads();
    int woff = 0;
#pragma unroll
    for (int w = 0; w < 4; ++w) if (w < (t >> 6)) woff += wtot[w];
    int excl = incl - v + woff;

    int node = b * 256 + t;
    if (node < nN) rowStart[node] = beg + excl;
    __syncthreads();
    hcnt[t] = beg + excl;   // reuse as cursor
    __syncthreads();

    for (int i = t; i < cnt; i += 256) {
        int2 e = (i < BCAP) ? stage[i] : packed[beg + i];
        int dl = (e.x >> 20) & 255;
        int pos = atomicAdd(&hcnt[dl], 1);
        se[pos] = make_int2(e.x & 0xFFFFF, e.y);
    }
}

// ---------------- Fused aggregation ----------------------------------------
// agg[n] = sum_e w_e * h[src_e]; 4 threads per node (one float4 slice each).
// EPI==0: epilogue h2 = relu(agg + b1) @ Wn   (full 16-vec via quad shuffles)
// EPI==1: epilogue out = log_softmax(agg + b2)
template <int EPI>
__global__ __launch_bounds__(256) void gather_fused_kernel(
    const int* __restrict__ rowStart, const int2* __restrict__ se,
    const float* __restrict__ h, const float* __restrict__ bias,
    const float* __restrict__ Wn, float* __restrict__ outp, int nN)
{
    __shared__ float sW[256];
    __shared__ float sb[16];
    if (EPI == 0) sW[threadIdx.x] = Wn[threadIdx.x];
    if (threadIdx.x < 16) sb[threadIdx.x] = bias[threadIdx.x];
    __syncthreads();

    int t = blockIdx.x * 256 + threadIdx.x;
    int n = t >> 2;
    if (n >= nN) return;          // quad-uniform: n identical across the quad
    int c4 = t & 3;
    int beg = rowStart[n], end = rowStart[n + 1];
    const float4* h4 = (const float4*)h;

    float ax = 0.f, ay = 0.f, az = 0.f, aw = 0.f;
    int p = beg;
    for (; p + 8 <= end; p += 8) {
        int2 ee[8];
        float4 vv[8];
#pragma unroll
        for (int j = 0; j < 8; ++j) ee[j] = se[p + j];
#pragma unroll
        for (int j = 0; j < 8; ++j)
            vv[j] = h4[(size_t)(unsigned)ee[j].x * 4 + c4];
#pragma unroll
        for (int j = 0; j < 8; ++j) {
            float w = __int_as_float(ee[j].y);
            ax = fmaf(w, vv[j].x, ax); ay = fmaf(w, vv[j].y, ay);
            az = fmaf(w, vv[j].z, az); aw = fmaf(w, vv[j].w, aw);
        }
    }
    if (p + 4 <= end) {
        int2 ee[4];
        float4 vv[4];
#pragma unroll
        for (int j = 0; j < 4; ++j) ee[j] = se[p + j];
#pragma unroll
        for (int j = 0; j < 4; ++j)
            vv[j] = h4[(size_t)(unsigned)ee[j].x * 4 + c4];
#pragma unroll
        for (int j = 0; j < 4; ++j) {
            float w = __int_as_float(ee[j].y);
            ax = fmaf(w, vv[j].x, ax); ay = fmaf(w, vv[j].y, ay);
            az = fmaf(w, vv[j].z, az); aw = fmaf(w, vv[j].w, aw);
        }
        p += 4;
    }
    for (; p < end; ++p) {
        int2 e = se[p];
        float4 v = h4[(size_t)(unsigned)e.x * 4 + c4];
        float w = __int_as_float(e.y);
        ax = fmaf(w, v.x, ax); ay = fmaf(w, v.y, ay);
        az = fmaf(w, v.z, az); aw = fmaf(w, v.w, aw);
    }

    int lane = threadIdx.x & 63;
    int lb = lane & ~3;           // quad base lane

    if (EPI == 0) {
        float v0 = fmaxf(ax + sb[c4 * 4 + 0], 0.f);
        float v1 = fmaxf(ay + sb[c4 * 4 + 1], 0.f);
        float v2 = fmaxf(az + sb[c4 * 4 + 2], 0.f);
        float v3 = fmaxf(aw + sb[c4 * 4 + 3], 0.f);
        float vk[16];
#pragma unroll
        for (int j = 0; j < 4; ++j) {
            vk[4 * j + 0] = __shfl(v0, lb + j, 64);
            vk[4 * j + 1] = __shfl(v1, lb + j, 64);
            vk[4 * j + 2] = __shfl(v2, lb + j, 64);
            vk[4 * j + 3] = __shfl(v3, lb + j, 64);
        }
        float o0 = 0.f, o1 = 0.f, o2 = 0.f, o3 = 0.f;
#pragma unroll
        for (int k = 0; k < 16; ++k) {
            float s = vk[k];
            o0 = fmaf(s, sW[k * 16 + c4 * 4 + 0], o0);
            o1 = fmaf(s, sW[k * 16 + c4 * 4 + 1], o1);
            o2 = fmaf(s, sW[k * 16 + c4 * 4 + 2], o2);
            o3 = fmaf(s, sW[k * 16 + c4 * 4 + 3], o3);
        }
        ((float4*)outp)[(size_t)n * 4 + c4] = make_float4(o0, o1, o2, o3);
    } else {
        float v0 = ax + sb[c4 * 4 + 0];
        float v1 = ay + sb[c4 * 4 + 1];
        float v2 = az + sb[c4 * 4 + 2];
        float v3 = aw + sb[c4 * 4 + 3];
        float m = fmaxf(fmaxf(v0, v1), fmaxf(v2, v3));
        m = fmaxf(m, __shfl_xor(m, 1, 64));
        m = fmaxf(m, __shfl_xor(m, 2, 64));
        float s = expf(v0 - m) + expf(v1 - m) + expf(v2 - m) + expf(v3 - m);
        s += __shfl_xor(s, 1, 64);
        s += __shfl_xor(s, 2, 64);
        float l = m + logf(s);
        ((float4*)outp)[(size_t)n * 4 + c4] =
            make_float4(v0 - l, v1 - l, v2 - l, v3 - l);
    }
}

extern "C" void kernel_launch(void* const* d_in, const int* in_sizes, int n_in,
                              void* d_out, int out_size, void* d_ws, size_t ws_size,
                              hipStream_t stream)
{
    const float* x  = (const float*)d_in[0];
    const void*  ei = d_in[1];
    const float* ew = (const float*)d_in[2];
    const float* W1 = (const float*)d_in[3];
    const float* b1 = (const float*)d_in[4];
    const float* W2 = (const float*)d_in[5];
    const float* b2 = (const float*)d_in[6];
    float* out = (float*)d_out;

    const int N = NN;
    const int E = in_sizes[2];

    const size_t featB = (size_t)N * HID * sizeof(float);           // 6.4 MB
    const size_t rowB  = (((size_t)(N + 1) * 4) + 255) & ~255ULL;
    const size_t bkB   = (((size_t)(NBUCK + 1) * 4) + 255) & ~255ULL;
    const size_t seB   = ((size_t)E * 8 + 255) & ~255ULL;           // 25.6 MB

    char* w = (char*)d_ws;
    float* buf0 = (float*)w;      w += (featB + 255) & ~255ULL;
    float* buf1 = (float*)w;      w += (featB + 255) & ~255ULL;
    int*   rowStart = (int*)w;    w += rowB;
    int*   bcnt = (int*)w;        w += bkB;
    int*   bbase = (int*)w;       w += bkB;
    int*   cursor = (int*)w;      w += bkB;
    int2*  se = (int2*)w;         w += seB;
    int2*  packed = (int2*)w;     w += seB;

    detect_idx_kernel<<<1, 64, 0, stream>>>((const long long*)ei, bcnt);

    // Fused gemm1 + bucket-hist (role-split grid; hist rides for free).
    const int gemmBlocks = (N + GTN - 1) / GTN;          // 391
    front_kernel<<<gemmBlocks + HISTB, 256, 0, stream>>>(
        x, W1, buf0, ei, bcnt, N, E, gemmBlocks);

    bucket_scan_kernel<<<1, 512, 0, stream>>>(bcnt, bbase, cursor, rowStart);
    bucketA_kernel<<<(E + EPB - 1) / EPB, 256, 0, stream>>>(ei, ew, cursor, packed, E);
    bucketB_kernel<<<NBUCK, 256, 0, stream>>>(packed, bbase, rowStart, se, N);

    const int nblocks4 = (N * 4 + 255) / 256;
    // Fused: gather+transform (h2 = relu(agg1+b1)@W2), gather+log_softmax.
    gather_fused_kernel<0><<<nblocks4, 256, 0, stream>>>(rowStart, se, buf0, b1, W2, buf1, N);
    gather_fused_kernel<1><<<nblocks4, 256, 0, stream>>>(rowStart, se, buf1, b2, W2, out, N);
}